// Round 2
// baseline (5578.616 us; speedup 1.0000x reference)
//
#include <hip/hip_runtime.h>
#include <hip/hip_bf16.h>
#include <math.h>

#define HEAD_DIM 128
#define NH 16
#define NKV 4
#define BB 4
#define TT 2048
#define DD 2048
#define ROWS (BB*TT)   // 8192

// ---------------------------------------------------------------------------
// GEMM: C[M,N] = A[M,K] @ W[N,K]^T   (both A and W are K-major row-major)
// 128x128 tile, BK=16, 256 threads, 8x8 micro-tile per thread.
// ---------------------------------------------------------------------------
__global__ __launch_bounds__(256, 2)
void sgemm_nt(const float* __restrict__ A, const float* __restrict__ W,
              float* __restrict__ C, int M, int N, int K)
{
    const int BK = 16;
    __shared__ float As[16][128];
    __shared__ float Bs[16][128];
    const int tid = threadIdx.x;
    const int bm = blockIdx.y * 128;
    const int bn = blockIdx.x * 128;
    const int tm = (tid >> 4) << 3;   // (tid/16)*8
    const int tn = (tid & 15) << 3;   // (tid%16)*8

    float acc[8][8];
    #pragma unroll
    for (int i = 0; i < 8; ++i)
        #pragma unroll
        for (int j = 0; j < 8; ++j) acc[i][j] = 0.f;

    const int lrow = tid >> 2;        // 0..63
    const int lc4  = (tid & 3) << 2;  // 0,4,8,12

    for (int kt = 0; kt < K; kt += BK) {
        #pragma unroll
        for (int l = 0; l < 2; ++l) {
            int row = lrow + l * 64;
            float4 va = *(const float4*)(A + (size_t)(bm + row) * K + kt + lc4);
            As[lc4 + 0][row] = va.x;
            As[lc4 + 1][row] = va.y;
            As[lc4 + 2][row] = va.z;
            As[lc4 + 3][row] = va.w;
            float4 vb = *(const float4*)(W + (size_t)(bn + row) * K + kt + lc4);
            Bs[lc4 + 0][row] = vb.x;
            Bs[lc4 + 1][row] = vb.y;
            Bs[lc4 + 2][row] = vb.z;
            Bs[lc4 + 3][row] = vb.w;
        }
        __syncthreads();
        #pragma unroll
        for (int k = 0; k < BK; ++k) {
            float a[8], b[8];
            *(float4*)&a[0] = *(const float4*)&As[k][tm];
            *(float4*)&a[4] = *(const float4*)&As[k][tm + 4];
            *(float4*)&b[0] = *(const float4*)&Bs[k][tn];
            *(float4*)&b[4] = *(const float4*)&Bs[k][tn + 4];
            #pragma unroll
            for (int i = 0; i < 8; ++i)
                #pragma unroll
                for (int j = 0; j < 8; ++j)
                    acc[i][j] = fmaf(a[i], b[j], acc[i][j]);
        }
        __syncthreads();
    }
    #pragma unroll
    for (int i = 0; i < 8; ++i) {
        float4 o0 = make_float4(acc[i][0], acc[i][1], acc[i][2], acc[i][3]);
        float4 o1 = make_float4(acc[i][4], acc[i][5], acc[i][6], acc[i][7]);
        *(float4*)(C + (size_t)(bm + tm + i) * N + bn + tn)     = o0;
        *(float4*)(C + (size_t)(bm + tm + i) * N + bn + tn + 4) = o1;
    }
}

// ---------------------------------------------------------------------------
// RoPE cos/sin table: cs[t*64+d] = cos(t * base^(-2d/128)), likewise sin.
// ---------------------------------------------------------------------------
__global__ void rope_table(float* __restrict__ cs, float* __restrict__ sn, float base)
{
    int idx = blockIdx.x * blockDim.x + threadIdx.x;
    if (idx >= TT * 64) return;
    int t = idx >> 6;
    int d = idx & 63;
    float inv = powf(base, -(float)(2 * d) / 128.0f);
    float f = (float)t * inv;
    cs[idx] = cosf(f);
    sn[idx] = sinf(f);
}

// ---------------------------------------------------------------------------
// Fused per-head RMSNorm + rotary + (optional) gain, in place.
// One 64-lane wave per row of 128: lane holds x[d] and x[d+64] (rotate-half pair).
// x layout: [B, T, heads, 128] flat; row index = (b*T + t)*heads + h.
// ---------------------------------------------------------------------------
__global__ __launch_bounds__(256)
void rmsrope(float* __restrict__ x, const float* __restrict__ cs,
             const float* __restrict__ sn, const float* __restrict__ gain,
             int heads, int use_gain)
{
    int row  = blockIdx.x * 4 + (threadIdx.x >> 6);
    int lane = threadIdx.x & 63;
    int h = row % heads;
    int t = (row / heads) % TT;
    size_t base = (size_t)row * HEAD_DIM;

    float x1 = x[base + lane];
    float x2 = x[base + 64 + lane];
    float ss = x1 * x1 + x2 * x2;
    #pragma unroll
    for (int m = 1; m < 64; m <<= 1) ss += __shfl_xor(ss, m, 64);
    float r = 1.0f / sqrtf(ss * (1.0f / 128.0f) + 1.1920929e-7f);
    x1 *= r; x2 *= r;

    float c = cs[t * 64 + lane];
    float s = sn[t * 64 + lane];
    float o1 =  x1 * c + x2 * s;
    float o2 = -x1 * s + x2 * c;
    if (use_gain) { float g = gain[h]; o1 *= g; o2 *= g; }
    x[base + lane]      = o1;
    x[base + 64 + lane] = o2;
}

// ---------------------------------------------------------------------------
// Causal flash attention, fp32, GQA (head h uses kv head h/4).
// Block: 256 threads; tile BQ=64 q rows x BK=64 k cols; D=128.
// Thread (ti,tj) = (tid/16, tid%16): S micro-tile rows i0=4*ti, cols j0=4*tj;
// PV/out: rows i0..i0+3, d-block dj=8*tj.
// y may alias q (block reads its own Q tile before writing its own Y tile).
// ---------------------------------------------------------------------------
#define BQ 64
#define BKT 64
#define QPAD 68
#define VPAD 132
#define PPAD 68

__global__ __launch_bounds__(256, 1)
void flash_attn(const float* __restrict__ q, const float* __restrict__ k,
                const float* __restrict__ v, float* __restrict__ y)
{
    const int qt = blockIdx.x;
    const int h  = blockIdx.y;
    const int b  = blockIdx.z;
    const int kvh = h >> 2;
    const int tid = threadIdx.x;
    const int ti = tid >> 4;
    const int tj = tid & 15;
    const int i0 = ti << 2;
    const int j0 = tj << 2;
    const int dj = tj << 3;

    __shared__ float Qs[HEAD_DIM][QPAD];  // transposed: Qs[d][i]
    __shared__ float Ks[HEAD_DIM][QPAD];  // transposed: Ks[d][j]
    __shared__ float Vs[BKT][VPAD];       // row-major:  Vs[j][d]
    __shared__ float Ps[BQ][PPAD];

    // stage Q tile (transposed)
    #pragma unroll
    for (int l = 0; l < 8; ++l) {
        int idx = tid + (l << 8);
        int i  = idx >> 5;
        int d4 = (idx & 31) << 2;
        const float* src = q + ((size_t)((b * TT + qt * BQ + i) * NH + h)) * HEAD_DIM + d4;
        float4 vq = *(const float4*)src;
        Qs[d4 + 0][i] = vq.x;
        Qs[d4 + 1][i] = vq.y;
        Qs[d4 + 2][i] = vq.z;
        Qs[d4 + 3][i] = vq.w;
    }

    const float scale = 0.08838834764831845f;  // 1/sqrt(128)
    float m_run[4], l_run[4], o[4][8];
    #pragma unroll
    for (int r = 0; r < 4; ++r) {
        m_run[r] = -INFINITY;
        l_run[r] = 0.f;
        #pragma unroll
        for (int d = 0; d < 8; ++d) o[r][d] = 0.f;
    }

    for (int kt = 0; kt <= qt; ++kt) {
        // stage K (transposed) and V tiles
        #pragma unroll
        for (int l = 0; l < 8; ++l) {
            int idx = tid + (l << 8);
            int j  = idx >> 5;
            int d4 = (idx & 31) << 2;
            size_t gb = ((size_t)((b * TT + kt * BKT + j) * NKV + kvh)) * HEAD_DIM + d4;
            float4 vk = *(const float4*)(k + gb);
            Ks[d4 + 0][j] = vk.x;
            Ks[d4 + 1][j] = vk.y;
            Ks[d4 + 2][j] = vk.z;
            Ks[d4 + 3][j] = vk.w;
            float4 vv = *(const float4*)(v + gb);
            *(float4*)&Vs[j][d4] = vv;
        }
        __syncthreads();

        // S = (Q K^T) * scale
        float s[4][4];
        #pragma unroll
        for (int r = 0; r < 4; ++r)
            #pragma unroll
            for (int c = 0; c < 4; ++c) s[r][c] = 0.f;

        #pragma unroll 8
        for (int d = 0; d < HEAD_DIM; ++d) {
            float4 qv = *(const float4*)&Qs[d][i0];
            float4 kv = *(const float4*)&Ks[d][j0];
            float qa[4] = {qv.x, qv.y, qv.z, qv.w};
            float ka[4] = {kv.x, kv.y, kv.z, kv.w};
            #pragma unroll
            for (int r = 0; r < 4; ++r)
                #pragma unroll
                for (int c = 0; c < 4; ++c)
                    s[r][c] = fmaf(qa[r], ka[c], s[r][c]);
        }
        #pragma unroll
        for (int r = 0; r < 4; ++r)
            #pragma unroll
            for (int c = 0; c < 4; ++c) s[r][c] *= scale;

        if (kt == qt) {
            #pragma unroll
            for (int r = 0; r < 4; ++r)
                #pragma unroll
                for (int c = 0; c < 4; ++c)
                    if (j0 + c > i0 + r) s[r][c] = -INFINITY;
        }

        // online softmax (row groups of 16 lanes share a row set)
        float p[4][4];
        #pragma unroll
        for (int r = 0; r < 4; ++r) {
            float mx = fmaxf(fmaxf(s[r][0], s[r][1]), fmaxf(s[r][2], s[r][3]));
            #pragma unroll
            for (int m = 1; m < 16; m <<= 1) mx = fmaxf(mx, __shfl_xor(mx, m, 64));
            float mtot = fmaxf(m_run[r], mx);
            float al = expf(m_run[r] - mtot);
            float rs = 0.f;
            #pragma unroll
            for (int c = 0; c < 4; ++c) {
                p[r][c] = expf(s[r][c] - mtot);
                rs += p[r][c];
            }
            #pragma unroll
            for (int m = 1; m < 16; m <<= 1) rs += __shfl_xor(rs, m, 64);
            l_run[r] = l_run[r] * al + rs;
            m_run[r] = mtot;
            #pragma unroll
            for (int d = 0; d < 8; ++d) o[r][d] *= al;
        }

        // share P through LDS
        #pragma unroll
        for (int r = 0; r < 4; ++r)
            #pragma unroll
            for (int c = 0; c < 4; ++c)
                Ps[i0 + r][j0 + c] = p[r][c];
        __syncthreads();

        // O += P @ V
        #pragma unroll 4
        for (int j = 0; j < BKT; ++j) {
            float4 v0 = *(const float4*)&Vs[j][dj];
            float4 v1 = *(const float4*)&Vs[j][dj + 4];
            float va[8] = {v0.x, v0.y, v0.z, v0.w, v1.x, v1.y, v1.z, v1.w};
            #pragma unroll
            for (int r = 0; r < 4; ++r) {
                float pr = Ps[i0 + r][j];
                #pragma unroll
                for (int d = 0; d < 8; ++d)
                    o[r][d] = fmaf(pr, va[d], o[r][d]);
            }
        }
        __syncthreads();
    }

    // epilogue: normalize and store
    #pragma unroll
    for (int r = 0; r < 4; ++r) {
        float inv = 1.0f / l_run[r];
        float4 o0 = make_float4(o[r][0] * inv, o[r][1] * inv, o[r][2] * inv, o[r][3] * inv);
        float4 o1 = make_float4(o[r][4] * inv, o[r][5] * inv, o[r][6] * inv, o[r][7] * inv);
        float* dst = y + ((size_t)((b * TT + qt * BQ + i0 + r) * NH + h)) * HEAD_DIM + dj;
        *(float4*)dst       = o0;
        *(float4*)(dst + 4) = o1;
    }
}

// ---------------------------------------------------------------------------
extern "C" void kernel_launch(void* const* d_in, const int* in_sizes, int n_in,
                              void* d_out, int out_size, void* d_ws, size_t ws_size,
                              hipStream_t stream)
{
    const float* x      = (const float*)d_in[0];
    const float* q_w    = (const float*)d_in[1];
    const float* k_w    = (const float*)d_in[2];
    const float* v_w    = (const float*)d_in[3];
    const float* out_w  = (const float*)d_in[4];
    const float* q_gain = (const float*)d_in[5];
    float* out = (float*)d_out;

    char* ws = (char*)d_ws;
    float* qb = (float*)ws;                                   // [8192][2048]
    float* kb = (float*)(ws + (size_t)ROWS * DD * 4);         // [8192][512]
    float* vb = kb + (size_t)ROWS * (NKV * HEAD_DIM);         // [8192][512]
    float* cs = vb + (size_t)ROWS * (NKV * HEAD_DIM);         // [2048][64]
    float* sn = cs + TT * 64;                                 // [2048][64]

    dim3 blk(256);

    // projections
    sgemm_nt<<<dim3(DD / 128, ROWS / 128), blk, 0, stream>>>(x, q_w, qb, ROWS, DD, DD);
    sgemm_nt<<<dim3((NKV * HEAD_DIM) / 128, ROWS / 128), blk, 0, stream>>>(x, k_w, kb, ROWS, NKV * HEAD_DIM, DD);
    sgemm_nt<<<dim3((NKV * HEAD_DIM) / 128, ROWS / 128), blk, 0, stream>>>(x, v_w, vb, ROWS, NKV * HEAD_DIM, DD);

    // rope table (T=2048 > train 1024 -> NTK base scaling)
    double sc = (double)TT / 1024.0;
    double base = 10000.0 * pow(sc, 128.0 / 126.0);
    rope_table<<<(TT * 64 + 255) / 256, blk, 0, stream>>>(cs, sn, (float)base);

    // fused rmsnorm + rope (+ gain for q), in place
    rmsrope<<<(ROWS * NH) / 4, blk, 0, stream>>>(qb, cs, sn, q_gain, NH, 1);
    rmsrope<<<(ROWS * NKV) / 4, blk, 0, stream>>>(kb, cs, sn, nullptr, NKV, 0);

    // attention; y aliases the q buffer (safe: each block reads only its own
    // Q tile, then writes only that tile's Y rows)
    flash_attn<<<dim3(TT / BQ, NH, BB), blk, 0, stream>>>(qb, kb, vb, qb);

    // output projection
    sgemm_nt<<<dim3(DD / 128, ROWS / 128), blk, 0, stream>>>(qb, out_w, out, ROWS, DD, DD);
}

// Round 3
// 754.774 us; speedup vs baseline: 7.3911x; 7.3911x over previous
//
#include <hip/hip_runtime.h>
#include <math.h>

#define HEAD_DIM 128
#define NH 16
#define NKV 4
#define BB 4
#define TT 2048
#define DD 2048
#define ROWS (BB*TT)   // 8192

typedef unsigned short u16;
typedef __attribute__((ext_vector_type(8))) short short8;
typedef __attribute__((ext_vector_type(4))) float f32x4;
typedef __attribute__((ext_vector_type(4))) unsigned short u16x4;

__device__ __forceinline__ float bf2f(u16 u) {
    union { unsigned int i; float f; } v; v.i = ((unsigned int)u) << 16; return v.f;
}
__device__ __forceinline__ u16 f2bf(float f) {
    union { float f; unsigned int i; } v; v.f = f;
    unsigned int r = v.i + 0x7FFFu + ((v.i >> 16) & 1u);   // round-to-nearest-even
    return (u16)(r >> 16);
}
__device__ __forceinline__ f32x4 mfma16(short8 a, short8 b, f32x4 c) {
    return __builtin_amdgcn_mfma_f32_16x16x32_bf16(a, b, c, 0, 0, 0);
}

// ---------------------------------------------------------------------------
// fp32 -> bf16 cast (n multiple of 4; grid covers exactly)
// ---------------------------------------------------------------------------
__global__ __launch_bounds__(256)
void cast_f2b(const float* __restrict__ in, u16* __restrict__ out, int n)
{
    int i = (blockIdx.x * 256 + threadIdx.x) * 4;
    if (i >= n) return;
    float4 v = *(const float4*)(in + i);
    u16x4 o;
    o.x = f2bf(v.x); o.y = f2bf(v.y); o.z = f2bf(v.z); o.w = f2bf(v.w);
    *(u16x4*)(out + i) = o;
}

// ---------------------------------------------------------------------------
// RoPE tables
// ---------------------------------------------------------------------------
__global__ __launch_bounds__(256)
void rope_table(float* __restrict__ cs, float* __restrict__ sn, float base)
{
    int idx = blockIdx.x * 256 + threadIdx.x;
    if (idx >= TT * 64) return;
    int t = idx >> 6;
    int d = idx & 63;
    float inv = powf(base, -(float)(2 * d) / 128.0f);
    float f = (float)t * inv;
    cs[idx] = cosf(f);
    sn[idx] = sinf(f);
}

// ---------------------------------------------------------------------------
// Fused per-head RMSNorm + rotary (+gain), in place on bf16 rows of 128.
// One 64-lane wave per row; lane holds pair (d, d+64).
// ---------------------------------------------------------------------------
__global__ __launch_bounds__(256)
void rmsrope_bf16(u16* __restrict__ x, const float* __restrict__ cs,
                  const float* __restrict__ sn, const float* __restrict__ gain,
                  int heads, int use_gain)
{
    int row  = blockIdx.x * 4 + (threadIdx.x >> 6);
    int lane = threadIdx.x & 63;
    int h = row % heads;
    int t = (row / heads) % TT;
    size_t base = (size_t)row * HEAD_DIM;

    float x1 = bf2f(x[base + lane]);
    float x2 = bf2f(x[base + 64 + lane]);
    float ss = x1 * x1 + x2 * x2;
    #pragma unroll
    for (int m = 1; m < 64; m <<= 1) ss += __shfl_xor(ss, m, 64);
    float r = 1.0f / sqrtf(ss * (1.0f / 128.0f) + 1.1920929e-7f);
    x1 *= r; x2 *= r;

    float c = cs[t * 64 + lane];
    float s = sn[t * 64 + lane];
    float o1 =  x1 * c + x2 * s;
    float o2 = -x1 * s + x2 * c;
    if (use_gain) { float g = gain[h]; o1 *= g; o2 *= g; }
    x[base + lane]      = f2bf(o1);
    x[base + 64 + lane] = f2bf(o2);
}

// ---------------------------------------------------------------------------
// V transpose+relayout: vbh [B,T,KVH,128] -> vtb [B,KVH,128,T]   (bf16)
// ---------------------------------------------------------------------------
__global__ __launch_bounds__(256)
void transpose_v(const u16* __restrict__ vbh, u16* __restrict__ vtb)
{
    __shared__ u16 tile[64][72];
    const int tb = blockIdx.x;        // t block (64)
    const int db = blockIdx.y;        // d block (64)
    const int z  = blockIdx.z;        // b*NKV + kvh
    const int tid = threadIdx.x;

    {
        const int r = tid >> 2, cq = tid & 3;
        const u16* src = vbh + ((size_t)(((z >> 2) * TT + tb * 64 + r) * NKV + (z & 3))) * 128
                             + db * 64 + cq * 16;
        short8 s0 = *(const short8*)(src);
        short8 s1 = *(const short8*)(src + 8);
        #pragma unroll
        for (int e = 0; e < 8; ++e) tile[r][cq * 16 + e]     = (u16)s0[e];
        #pragma unroll
        for (int e = 0; e < 8; ++e) tile[r][cq * 16 + 8 + e] = (u16)s1[e];
    }
    __syncthreads();
    {
        const int d = tid >> 2, tq = tid & 3;
        __attribute__((aligned(16))) u16 tmp[16];
        #pragma unroll
        for (int e = 0; e < 16; ++e) tmp[e] = tile[tq * 16 + e][d];
        u16* dst = vtb + ((size_t)(z * 128 + db * 64 + d)) * TT + tb * 64 + tq * 16;
        *(short8*)(dst)     = ((short8*)tmp)[0];
        *(short8*)(dst + 8) = ((short8*)tmp)[1];
    }
}

// ---------------------------------------------------------------------------
// bf16 MFMA GEMM: C[M,N] = A[M,K] @ W[N,K]^T ; A,W bf16 K-major; C fp32 or bf16.
// 128x128 tile, BK=32, 4 waves (2x2 of 64x64), 16x16x32 MFMA.
// LDS pad: 40 elems/row -> conflict-free b128 reads and writes.
// ---------------------------------------------------------------------------
#define LDP 40

template<int OUT_BF16>
__global__ __launch_bounds__(256)
void gemm_bf16_nt(const u16* __restrict__ A, const u16* __restrict__ W,
                  void* __restrict__ Cout, int M, int N, int K)
{
    __shared__ u16 As[128 * LDP];
    __shared__ u16 Bs[128 * LDP];
    const int tid = threadIdx.x;
    const int l = tid & 63, w = tid >> 6;
    const int lq = l & 15, lg = l >> 4;
    const int bm = blockIdx.y << 7, bn = blockIdx.x << 7;
    const int wr = (w >> 1) << 6, wc = (w & 1) << 6;

    f32x4 acc[4][4];
    #pragma unroll
    for (int m = 0; m < 4; ++m)
        #pragma unroll
        for (int n = 0; n < 4; ++n)
            acc[m][n] = (f32x4){0.f, 0.f, 0.f, 0.f};

    const int srow = tid >> 1;            // 0..127
    const int scol = (tid & 1) << 4;      // 0 / 16
    const u16* arow = A + (size_t)(bm + srow) * K + scol;
    const u16* brow = W + (size_t)(bn + srow) * K + scol;
    u16* asd = As + srow * LDP + scol;
    u16* bsd = Bs + srow * LDP + scol;

    for (int kt = 0; kt < K; kt += 32) {
        short8 va0 = *(const short8*)(arow + kt);
        short8 va1 = *(const short8*)(arow + kt + 8);
        short8 vb0 = *(const short8*)(brow + kt);
        short8 vb1 = *(const short8*)(brow + kt + 8);
        __syncthreads();                       // prior iter LDS reads done
        *(short8*)(asd)     = va0;
        *(short8*)(asd + 8) = va1;
        *(short8*)(bsd)     = vb0;
        *(short8*)(bsd + 8) = vb1;
        __syncthreads();

        short8 af[4], bf[4];
        #pragma unroll
        for (int m = 0; m < 4; ++m)
            af[m] = *(const short8*)(As + (wr + m * 16 + lq) * LDP + lg * 8);
        #pragma unroll
        for (int n = 0; n < 4; ++n)
            bf[n] = *(const short8*)(Bs + (wc + n * 16 + lq) * LDP + lg * 8);
        #pragma unroll
        for (int m = 0; m < 4; ++m)
            #pragma unroll
            for (int n = 0; n < 4; ++n)
                acc[m][n] = mfma16(af[m], bf[n], acc[m][n]);
    }

    // C/D layout: col = lane&15, row = (lane>>4)*4 + reg
    #pragma unroll
    for (int m = 0; m < 4; ++m) {
        int grow = bm + wr + m * 16 + lg * 4;
        #pragma unroll
        for (int n = 0; n < 4; ++n) {
            int gcol = bn + wc + n * 16 + lq;
            #pragma unroll
            for (int q = 0; q < 4; ++q) {
                if (OUT_BF16)
                    ((u16*)Cout)[(size_t)(grow + q) * N + gcol] = f2bf(acc[m][n][q]);
                else
                    ((float*)Cout)[(size_t)(grow + q) * N + gcol] = acc[m][n][q];
            }
        }
    }
}

// ---------------------------------------------------------------------------
// Causal MFMA flash attention (bf16 in, bf16 out), GQA 4:1.
// Block: 256 thr (4 waves); tile 64 q-rows x 64 keys; D=128.
// Wave w owns q-rows w*16..w*16+15. Q in registers. K tile and V^T tile in
// LDS with XOR swizzle (byte ^= (row&7)<<4). P via per-wave-private LDS stripe.
// Online softmax in exp2 domain (scale*log2e folded).
// ---------------------------------------------------------------------------
__global__ __launch_bounds__(256)
void attn_mfma(const u16* __restrict__ qg, const u16* __restrict__ kg,
               const u16* __restrict__ vtg, u16* __restrict__ yg)
{
    __shared__ u16 Ks[64 * 128];    // [key][d]    swizzled
    __shared__ u16 Vt[128 * 64];    // [d][key]    swizzled
    __shared__ u16 Ps[64 * 64];     // [qrow][key] swizzled, wave-private stripes

    const int qt = 31 - (int)blockIdx.x;       // heavy tiles first
    const int h = blockIdx.y, b = blockIdx.z, kvh = h >> 2;
    const int tid = threadIdx.x, w = tid >> 6, l = tid & 63;
    const int lq = l & 15, lg = l >> 4;

    // Q fragments (lane lq holds q-row w*16+lq; 4 k-slices of 8 bf16)
    const int qtok = qt * 64 + w * 16 + lq;
    const u16* qrow = qg + ((size_t)((b * TT + qtok) * NH + h) << 7);
    short8 qf[4];
    #pragma unroll
    for (int s = 0; s < 4; ++s)
        qf[s] = *(const short8*)(qrow + s * 32 + lg * 8);

    f32x4 o[8];
    #pragma unroll
    for (int nf = 0; nf < 8; ++nf) o[nf] = (f32x4){0.f, 0.f, 0.f, 0.f};
    float m2[4], lr[4];
    #pragma unroll
    for (int q = 0; q < 4; ++q) { m2[q] = -INFINITY; lr[q] = 0.f; }

    const float sc2 = 0.08838834764831845f * 1.4426950408889634f; // 1/sqrt(128)*log2e

    // staging decomposition
    const int kj = tid >> 2, kpart = tid & 3;   // K: key row, 64B quarter
    const int vd = tid >> 1, vhalf = tid & 1;   // Vt: d row, 64B half
    const u16* kbase = kg + ((size_t)((b * TT + kj) * NKV + kvh) << 7) + kpart * 32;
    const u16* vbase = vtg + (((size_t)((b * NKV + kvh) * 128 + vd)) << 11) + vhalf * 32;
    char* KsB = (char*)Ks; char* VtB = (char*)Vt; char* PsB = (char*)Ps;
    const int kwoff = kj * 256 + kpart * 64;
    const int kxor = (kj & 7) << 4;
    const int vwoff = vd * 128 + vhalf * 64;
    const int vxor = (vd & 7) << 4;

    for (int kt = 0; kt <= qt; ++kt) {
        const u16* ksrc = kbase + (size_t)kt * 64 * (NKV * HEAD_DIM);
        const u16* vsrc = vbase + kt * 64;
        short8 kv0 = *(const short8*)(ksrc);
        short8 kv1 = *(const short8*)(ksrc + 8);
        short8 kv2 = *(const short8*)(ksrc + 16);
        short8 kv3 = *(const short8*)(ksrc + 24);
        short8 vv0 = *(const short8*)(vsrc);
        short8 vv1 = *(const short8*)(vsrc + 8);
        short8 vv2 = *(const short8*)(vsrc + 16);
        short8 vv3 = *(const short8*)(vsrc + 24);
        __syncthreads();                          // prior iter LDS reads done
        *(short8*)(KsB + ((kwoff +  0) ^ kxor)) = kv0;
        *(short8*)(KsB + ((kwoff + 16) ^ kxor)) = kv1;
        *(short8*)(KsB + ((kwoff + 32) ^ kxor)) = kv2;
        *(short8*)(KsB + ((kwoff + 48) ^ kxor)) = kv3;
        *(short8*)(VtB + ((vwoff +  0) ^ vxor)) = vv0;
        *(short8*)(VtB + ((vwoff + 16) ^ vxor)) = vv1;
        *(short8*)(VtB + ((vwoff + 32) ^ vxor)) = vv2;
        *(short8*)(VtB + ((vwoff + 48) ^ vxor)) = vv3;
        __syncthreads();

        // ---- S = Q K^T (16 MFMA) ----
        f32x4 s[4];
        #pragma unroll
        for (int n = 0; n < 4; ++n) s[n] = (f32x4){0.f, 0.f, 0.f, 0.f};
        #pragma unroll
        for (int n = 0; n < 4; ++n) {
            const int jrow = n * 16 + lq;
            const int jx = (jrow & 7) << 4;
            #pragma unroll
            for (int ss = 0; ss < 4; ++ss) {
                short8 kf = *(const short8*)(KsB + (((jrow << 8) + (ss << 6) + (lg << 4)) ^ jx));
                s[n] = mfma16(qf[ss], kf, s[n]);
            }
        }

        // ---- scale + causal mask ----
        float p[4][4];
        const bool diag = (kt == qt);
        #pragma unroll
        for (int n = 0; n < 4; ++n) {
            const int gcol = kt * 64 + n * 16 + lq;
            #pragma unroll
            for (int q = 0; q < 4; ++q) {
                float val = s[n][q] * sc2;
                if (diag && (gcol > qt * 64 + w * 16 + lg * 4 + q)) val = -INFINITY;
                p[n][q] = val;
            }
        }

        // ---- online softmax (rows live in 16-lane groups) ----
        #pragma unroll
        for (int q = 0; q < 4; ++q) {
            float mx = fmaxf(fmaxf(p[0][q], p[1][q]), fmaxf(p[2][q], p[3][q]));
            mx = fmaxf(mx, __shfl_xor(mx, 1, 64));
            mx = fmaxf(mx, __shfl_xor(mx, 2, 64));
            mx = fmaxf(mx, __shfl_xor(mx, 4, 64));
            mx = fmaxf(mx, __shfl_xor(mx, 8, 64));
            float mn = fmaxf(m2[q], mx);
            float al = exp2f(m2[q] - mn);
            m2[q] = mn;
            float rs = 0.f;
            #pragma unroll
            for (int n = 0; n < 4; ++n) {
                float e = exp2f(p[n][q] - mn);
                p[n][q] = e;
                rs += e;
            }
            rs += __shfl_xor(rs, 1, 64); rs += __shfl_xor(rs, 2, 64);
            rs += __shfl_xor(rs, 4, 64); rs += __shfl_xor(rs, 8, 64);
            lr[q] = lr[q] * al + rs;
            #pragma unroll
            for (int nf = 0; nf < 8; ++nf) o[nf][q] *= al;
        }

        // ---- P -> LDS (bf16, wave-private stripe, swizzled) ----
        #pragma unroll
        for (int n = 0; n < 4; ++n)
            #pragma unroll
            for (int q = 0; q < 4; ++q) {
                const int prow = w * 16 + lg * 4 + q;
                const int pcol = n * 16 + lq;
                *(u16*)(PsB + (((prow << 7) + (pcol << 1)) ^ ((prow & 7) << 4))) = f2bf(p[n][q]);
            }

        // ---- O += P V (16 MFMA) ----
        {
            const int prow = w * 16 + lq;
            const int px = (prow & 7) << 4;
            #pragma unroll
            for (int s2 = 0; s2 < 2; ++s2) {
                short8 pa = *(const short8*)(PsB + (((prow << 7) + (s2 << 6) + (lg << 4)) ^ px));
                #pragma unroll
                for (int nf = 0; nf < 8; ++nf) {
                    const int drow = nf * 16 + lq;
                    short8 vf = *(const short8*)(VtB + (((drow << 7) + (s2 << 6) + (lg << 4)) ^ ((drow & 7) << 4)));
                    o[nf] = mfma16(pa, vf, o[nf]);
                }
            }
        }
    }

    // ---- epilogue ----
    #pragma unroll
    for (int q = 0; q < 4; ++q) {
        float inv = 1.0f / lr[q];
        const int trow = qt * 64 + w * 16 + lg * 4 + q;
        u16* ydst = yg + ((size_t)((b * TT + trow) * NH + h) << 7);
        #pragma unroll
        for (int nf = 0; nf < 8; ++nf)
            ydst[nf * 16 + lq] = f2bf(o[nf][q] * inv);
    }
}

// ---------------------------------------------------------------------------
extern "C" void kernel_launch(void* const* d_in, const int* in_sizes, int n_in,
                              void* d_out, int out_size, void* d_ws, size_t ws_size,
                              hipStream_t stream)
{
    const float* x      = (const float*)d_in[0];
    const float* q_w    = (const float*)d_in[1];
    const float* k_w    = (const float*)d_in[2];
    const float* v_w    = (const float*)d_in[3];
    const float* out_w  = (const float*)d_in[4];
    const float* q_gain = (const float*)d_in[5];
    float* out = (float*)d_out;

    char* ws = (char*)d_ws;
    u16* qh   = (u16*)(ws);                       // 33,554,432 B
    u16* kh   = (u16*)(ws + 33554432ull);         //  8,388,608
    u16* vbh  = (u16*)(ws + 41943040ull);         //  8,388,608
    u16* vtb  = (u16*)(ws + 50331648ull);         //  8,388,608
    u16* xh   = (u16*)(ws + 58720256ull);         // 33,554,432 (xh, later y)
    u16* wbuf = (u16*)(ws + 92274688ull);         //  8,388,608 (shared weight buf)
    float* cs = (float*)(ws + 100663296ull);      //    524,288
    float* sn = cs + TT * 64;                     //    524,288  (total 101,711,872)

    dim3 blk(256);

    // rope tables (T=2048 > train 1024 -> NTK base scaling)
    double base = 10000.0 * pow((double)TT / 1024.0, 128.0 / 126.0);
    rope_table<<<(TT * 64) / 256, blk, 0, stream>>>(cs, sn, (float)base);

    // cast activations
    cast_f2b<<<(ROWS * DD) / 1024, blk, 0, stream>>>(x, xh, ROWS * DD);

    // projections (weight cast -> gemm, shared weight buffer)
    cast_f2b<<<(DD * DD) / 1024, blk, 0, stream>>>(q_w, wbuf, DD * DD);
    gemm_bf16_nt<1><<<dim3(DD / 128, ROWS / 128), blk, 0, stream>>>(xh, wbuf, qh, ROWS, DD, DD);
    cast_f2b<<<(512 * DD) / 1024, blk, 0, stream>>>(k_w, wbuf, 512 * DD);
    gemm_bf16_nt<1><<<dim3(512 / 128, ROWS / 128), blk, 0, stream>>>(xh, wbuf, kh, ROWS, 512, DD);
    cast_f2b<<<(512 * DD) / 1024, blk, 0, stream>>>(v_w, wbuf, 512 * DD);
    gemm_bf16_nt<1><<<dim3(512 / 128, ROWS / 128), blk, 0, stream>>>(xh, wbuf, vbh, ROWS, 512, DD);

    // fused rmsnorm + rope (+gain for q), in place on bf16
    rmsrope_bf16<<<(ROWS * NH) / 4, blk, 0, stream>>>(qh, cs, sn, q_gain, NH, 1);
    rmsrope_bf16<<<(ROWS * NKV) / 4, blk, 0, stream>>>(kh, cs, sn, nullptr, NKV, 0);

    // V -> [B,KVH,128,T]
    transpose_v<<<dim3(TT / 64, 2, BB * NKV), blk, 0, stream>>>(vbh, vtb);

    // attention -> y (reuses xh region; xh no longer needed)
    attn_mfma<<<dim3(TT / 64, NH, BB), blk, 0, stream>>>(qh, kh, vtb, xh);

    // output projection (fp32 out)
    cast_f2b<<<(DD * DD) / 1024, blk, 0, stream>>>(out_w, wbuf, DD * DD);
    gemm_bf16_nt<0><<<dim3(DD / 128, ROWS / 128), blk, 0, stream>>>(xh, wbuf, out, ROWS, DD, DD);
}